// Round 3
// baseline (11.126 us; speedup 1.0000x reference)
//
#include <hip/hip_runtime.h>
#include <math.h>

// MMLU Llama head: RMSNorm(last token) -> 4-row GEMV -> softmax(4).
// Only x[last] and 4 rows of head_weight are live (~96 KB). Single-block
// latency-bound kernel; we are near the graph-replay launch floor.
//
// R3: (1) sum-of-squares reuses option-group-0's x loads (its dot loop
// covers all 1024 float4 of the x row) -- removes the separate x4[tid]
// load for all threads; (2) parallel wave-0 tail replaces the serial
// thread-0 tail: shuffle-reduce partials, 4 parallel expf on lanes
// 0/4/8/12, direct writes. Fixed reduction order -> deterministic.

constexpr int D_MODEL = 4096;
constexpr int SEQ     = 2048;
constexpr int NOPT    = 4;

__global__ __launch_bounds__(1024) void mmlu_head_kernel(
    const float* __restrict__ x,        // [SEQ, D_MODEL]
    const float* __restrict__ nw,       // [D_MODEL]
    const float* __restrict__ hw,       // [VOCAB, D_MODEL]
    const int*   __restrict__ opt,      // [NOPT]
    float*       __restrict__ out)      // [NOPT]
{
    __shared__ float s_dot[16];         // per-wave dot partials (option = wid>>2)
    __shared__ float s_ss[4];           // ss partials from option-group 0's waves

    const int tid  = threadIdx.x;       // 0..1023
    const int lane = tid & 63;
    const int wid  = tid >> 6;          // 0..15
    const int g    = tid >> 8;          // option 0..3 (wave-uniform)
    const int gt   = tid & 255;         // thread within option group

    // Load option index first so the dependent head-row loads issue early.
    const int row = opt[g];
    const float4* h4 = reinterpret_cast<const float4*>(hw + (size_t)row * D_MODEL);
    const float4* x4 = reinterpret_cast<const float4*>(x + (size_t)(SEQ - 1) * D_MODEL);
    const float4* w4 = reinterpret_cast<const float4*>(nw);

    // dot_g = sum_d hw[row][d] * x[d] * nw[d]; group 0 also accumulates ss.
    float dot = 0.f;
    float ss  = 0.f;
    #pragma unroll
    for (int it = 0; it < 4; ++it) {
        int i = gt + it * 256;          // group covers all 1024 float4
        float4 a  = h4[i];
        float4 xv = x4[i];
        float4 wv = w4[i];
        dot += a.x * xv.x * wv.x + a.y * xv.y * wv.y
             + a.z * xv.z * wv.z + a.w * xv.w * wv.w;
        if (g == 0)                      // wave-uniform branch
            ss += xv.x * xv.x + xv.y * xv.y + xv.z * xv.z + xv.w * xv.w;
    }

    // wave-level reductions
    #pragma unroll
    for (int o = 32; o > 0; o >>= 1) {
        dot += __shfl_down(dot, o, 64);
        if (g == 0) ss += __shfl_down(ss, o, 64);
    }
    if (lane == 0) {
        s_dot[wid] = dot;
        if (g == 0) s_ss[wid] = ss;     // wid 0..3 for group 0
    }
    __syncthreads();
    if (wid != 0) return;

    // ---- wave-0 parallel tail ----
    // lanes 0..15: dot partials; lanes 16..19: ss partials.
    float v = 0.f;
    if (lane < 16)               v = s_dot[lane];
    else if (lane < 20)          v = s_ss[lane - 16];
    // reduce groups of 4 (works for both ranges): lanes {0,4,8,12} and {16}
    v += __shfl_xor(v, 1, 64);
    v += __shfl_xor(v, 2, 64);
    // rms from lane 16's total
    float ssum = __shfl(v, 16, 64);
    const float rms = rsqrtf(ssum / (float)D_MODEL + 1e-5f);

    if (lane < 16 && (lane & 3) == 0) {
        float logit = v * rms;
        // max over lanes {0,4,8,12}
        float mx = fmaxf(logit, __shfl_xor(logit, 4, 64));
        mx = fmaxf(mx, __shfl_xor(mx, 8, 64));
        float e = expf(logit - mx);
        float denom = e + __shfl_xor(e, 4, 64);
        denom += __shfl_xor(denom, 8, 64);
        out[lane >> 2] = e / denom;
    }
}

extern "C" void kernel_launch(void* const* d_in, const int* in_sizes, int n_in,
                              void* d_out, int out_size, void* d_ws, size_t ws_size,
                              hipStream_t stream) {
    const float* x   = (const float*)d_in[0];   // [2048, 4096] f32
    const float* nw  = (const float*)d_in[1];   // [4096] f32
    const float* hw  = (const float*)d_in[2];   // [128256, 4096] f32
    const int*   opt = (const int*)d_in[3];     // [4] i32
    float* out = (float*)d_out;                 // [4] f32

    mmlu_head_kernel<<<1, 1024, 0, stream>>>(x, nw, hw, opt, out);
}